// Round 14
// baseline (136.866 us; speedup 1.0000x reference)
//
#include <hip/hip_runtime.h>

typedef short short8 __attribute__((ext_vector_type(8)));
typedef float floatx4 __attribute__((ext_vector_type(4)));
typedef unsigned uint2v __attribute__((ext_vector_type(2)));

#define INF 4096
#define TROWS 64
#define RS 528              // bf16 row stride: 512 B data + 16 B pad
#define TB (TROWS * RS)     // 33,792 B per buffer

// fp32 -> bf16 round-to-nearest-even (W prologue only)
__device__ __forceinline__ ushort f2bf(float f) {
  unsigned u = __builtin_bit_cast(unsigned, f);
  u += 0x7fffu + ((u >> 16) & 1u);
  return (ushort)(u >> 16);
}

// Block-diagonal GEMM v14 = v10 with TROWS 32 -> 64 (Little's-law fix).
// v13 post-mortem: depth-2 staging regressed (115us) -> per-load latency isn't
// the residual. Little's law: 24.6 GB/s/CU x ~1.4us latency needs ~37 KB reads
// in flight/CU; v10 had 32 KB and only part-time. v14 doubles the tile: LOADX
// = 8 rows/wave = 8 KB/wave = 64 KB/CU in flight, consumed one (2x longer)
// COMPUTE later; barrier count halves to 16. Everything else = v10 (108.5us):
// bf16-in-LDS cvt-once, 2 LDS bufs, raw s_barrier + lgkmcnt(0) per tile, NO
// vmcnt drains, compiler-managed vmcnt (spill-robust), W_k in regs, swapped
// mfma(W,x) -> D[n][m], dwordx4 coalesced IO (1 KB/row instructions).
// Grid 256 = 16 kb x 16 mg (1024 rows = 16 tiles of 64); 512 thr, 1 WG/CU.
__global__ __launch_bounds__(512, 1) void bd_gemm(
    const float* __restrict__ x, const float* __restrict__ W,
    const float* __restrict__ bias, float* __restrict__ out)
{
  __shared__ __align__(16) char xlds[2 * TB];  // 67,584 B

  const int bid  = blockIdx.x;
  const int kb   = bid & 15;   // xcd = bid%8 -> 2 k-blocks per XCD: W L2-resident
  const int mg   = bid >> 4;   // 0..15, 1024 rows each
  const int tid  = threadIdx.x;
  const int lane = tid & 63;
  const int w    = tid >> 6;   // wave 0..7 -> out-col slice of 32
  const int ln   = lane & 15;
  const int lk   = lane >> 4;  // 0..3

  const float* xbase = x   + (size_t)(mg * 1024) * INF + kb * 256;
  float*       obase = out + (size_t)(mg * 1024) * INF + kb * 256 + w * 32;

#define LGKM0_BAR()                                                           \
  do {                                                                        \
    asm volatile("s_waitcnt lgkmcnt(0)" ::: "memory");                        \
    __builtin_amdgcn_s_barrier();                                             \
    asm volatile("" ::: "memory");                                            \
  } while (0)

  floatx4 g[8];  // staging: 8 rows/wave/tile, 16 B/lane (32 VGPR)

  // one instruction = one contiguous 1 KB fp32 row -> regs (8 KB/wave in flight)
#define LOADX(t)                                                              \
  _Pragma("unroll") for (int i_ = 0; i_ < 8; ++i_)                            \
    g[i_] = *(const floatx4*)(xbase + (size_t)((t) * TROWS + w * 8 + i_) * INF + lane * 4);

  // cvt ONCE to bf16, ds_write_b64: row r gets bytes [lane*8, lane*8+8)
#define WRITEX(t)                                                             \
  _Pragma("unroll") for (int i_ = 0; i_ < 8; ++i_) {                          \
    const int r_ = w * 8 + i_;                                                \
    unsigned p0_, p1_;                                                        \
    asm("v_cvt_pk_bf16_f32 %0, %1, %2" : "=v"(p0_) : "v"(g[i_][0]), "v"(g[i_][1])); \
    asm("v_cvt_pk_bf16_f32 %0, %1, %2" : "=v"(p1_) : "v"(g[i_][2]), "v"(g[i_][3])); \
    uint2v u_; u_[0] = p0_; u_[1] = p1_;                                      \
    *(uint2v*)(xlds + ((t) & 1) * TB + r_ * RS + lane * 8) = u_;              \
  }

  // 32 ds_read_b128 + 64 MFMA per tile per wave (frag: x[mi*16+ln][kc*32+lk*8+e])
#define COMPUTE(t)                                                            \
  {                                                                           \
    const char* bb_ = xlds + ((t) & 1) * TB;                                  \
    _Pragma("unroll") for (int a_ = 0; a_ < 8; ++a_)                          \
      _Pragma("unroll") for (int e_ = 0; e_ < 4; ++e_) acc[a_][e_] = 0.0f;    \
    _Pragma("unroll") for (int kc_ = 0; kc_ < 8; ++kc_) {                     \
      short8 xf_[4];                                                          \
      _Pragma("unroll") for (int mi_ = 0; mi_ < 4; ++mi_)                     \
        xf_[mi_] = *(const short8*)(bb_ + (mi_ * 16 + ln) * RS + kc_ * 64 + lk * 16); \
      _Pragma("unroll") for (int mi_ = 0; mi_ < 4; ++mi_)                     \
        _Pragma("unroll") for (int ni_ = 0; ni_ < 2; ++ni_)                   \
          acc[mi_ * 2 + ni_] = __builtin_amdgcn_mfma_f32_16x16x32_bf16(       \
              wf[ni_][kc_], xf_[mi_], acc[mi_ * 2 + ni_], 0, 0, 0);           \
    }                                                                         \
  }

  // frag D[n][m]: m(row) = mi*16 + ln, n(col) = ni*16 + lk*4 + j -> dwordx4
#define STOREACC(t)                                                           \
  _Pragma("unroll") for (int mi_ = 0; mi_ < 4; ++mi_)                         \
    _Pragma("unroll") for (int ni_ = 0; ni_ < 2; ++ni_) {                     \
      floatx4 r_ = acc[mi_ * 2 + ni_];                                        \
      _Pragma("unroll") for (int j_ = 0; j_ < 4; ++j_) r_[j_] += bv[ni_][j_]; \
      *(floatx4*)(obase + (size_t)((t) * TROWS + mi_ * 16 + ln) * INF +       \
                  ni_ * 16 + lk * 4) = r_;                                    \
    }

  // ---- prologue: tile-0 loads first, W frags under their latency ----
  LOADX(0)

  short8 wf[2][8];  // wave w cols [w*32, w*32+32): A-layout [row=n (ln)][k=lk*8+e]
  {
    const float* wp = W + (size_t)kb * 65536 + (w * 32 + ln) * 256 + lk * 8;
#pragma unroll
    for (int ni = 0; ni < 2; ++ni)
#pragma unroll
      for (int kc = 0; kc < 8; ++kc) {
        const float* s = wp + ni * 16 * 256 + kc * 32;
        floatx4 v0 = *(const floatx4*)s;
        floatx4 v1 = *(const floatx4*)(s + 4);
        short8 u;
#pragma unroll
        for (int j = 0; j < 4; ++j) {
          u[j]     = (short)f2bf(v0[j]);
          u[4 + j] = (short)f2bf(v1[j]);
        }
        wf[ni][kc] = u;
      }
  }
  floatx4 bv[2];
#pragma unroll
  for (int ni = 0; ni < 2; ++ni)
    bv[ni] = *(const floatx4*)(bias + kb * 256 + w * 32 + ni * 16 + lk * 4);

  floatx4 acc[8];

  WRITEX(0)        // compiler's vmcnt wait for g sits here (after W prologue)
  LGKM0_BAR();

  // ---- main loop: 16 tiles of 64 rows, 1 barrier/tile, loads cross barriers --
#pragma unroll 1
  for (int t = 0; t < 16; ++t) {
    if (t < 15) LOADX(t + 1)   // 8 KB/wave in flight across the whole COMPUTE
    COMPUTE(t)
    STOREACC(t)
    if (t < 15) {
      WRITEX(t + 1)            // cvt once; ds_write bf16 into buf (t+1)&1
      LGKM0_BAR();             // ds_writes visible; NO vmcnt drain
    }
  }

#undef LGKM0_BAR
#undef LOADX
#undef WRITEX
#undef COMPUTE
#undef STOREACC
}

extern "C" void kernel_launch(void* const* d_in, const int* in_sizes, int n_in,
                              void* d_out, int out_size, void* d_ws, size_t ws_size,
                              hipStream_t stream) {
  const float* x = (const float*)d_in[0];
  const float* W = (const float*)d_in[1];
  const float* b = (const float*)d_in[2];
  float* out = (float*)d_out;
  // 16 k-blocks x 16 m-groups = 256 WGs (1/CU), 512 threads (8 waves)
  hipLaunchKernelGGL(bd_gemm, dim3(256), dim3(512), 0, stream, x, W, b, out);
}

// Round 15
// 114.228 us; speedup vs baseline: 1.1982x; 1.1982x over previous
//
#include <hip/hip_runtime.h>

typedef short short8 __attribute__((ext_vector_type(8)));
typedef float floatx4 __attribute__((ext_vector_type(4)));
typedef unsigned uint2v __attribute__((ext_vector_type(2)));

#define INF 4096
#define TROWS 32
#define FTB (TROWS * 1024)   // fp32 staging buffer: 32 rows x 1024 B = 32,768 B
#define RS 528               // bf16 row stride (512 B + 16 pad)
#define BTB (TROWS * RS)     // bf16 buffer: 16,896 B
#define BF16OFF (3 * FTB)    // bf16 bufs after the 3 fp32 staging bufs

// fp32 -> bf16 round-to-nearest-even (W prologue only)
__device__ __forceinline__ ushort f2bf(float f) {
  unsigned u = __builtin_bit_cast(unsigned, f);
  u += 0x7fffu + ((u >> 16) & 1u);
  return (ushort)(u >> 16);
}

// Block-diagonal GEMM v15 = v7 staging + v10 compute.
// v14: register staging can't scale in-flight bytes (VGPR-capped). v15 stages
// x fp32 via global_load_lds into a 3-buffer LDS ring (64-96 KB/CU in flight,
// ZERO staging VGPRs -- Little's law satisfied), then a per-tile CVT stage
// reads fp32 from LDS once, cvt_pk's, writes the bf16 tile (v10's cvt-once
// compute unchanged). Counted vmcnt is sound here: low VGPR pressure (~105) ->
// no spill VMEM pollution (v9's failure mode); iterations 0/1 peeled because
// their wait-counts differ from steady state (12).
// Steady-state count audit (loads certify via in-order vmcnt drain; stores in
// the count only strengthen): at iter-t top, newer-than-PF(t+1) =
// stores(t-2)[4] + PF(t+2)[4] + stores(t-1)[4] = 12 -> WAITVM(12).
// Ring safety: PF(t+3) overwrites fp32 buf t%3 whose reader CVT(t) ran before
// this iter's BAR; bf16 buf (t+1)&1's readers COMPUTE(t-1) likewise. ds_writes
// flushed by lgkmcnt(0)+s_barrier. No vmcnt(0) drains anywhere in the loop.
// Grid 256 = 16 kb x 16 mg (1024 rows = 32 tiles of 32); 512 thr, 1 WG/CU.
__global__ __launch_bounds__(512, 1) void bd_gemm(
    const float* __restrict__ x, const float* __restrict__ W,
    const float* __restrict__ bias, float* __restrict__ out)
{
  __shared__ __align__(16) char xlds[3 * FTB + 2 * BTB];  // 132,096 B

  const int bid  = blockIdx.x;
  const int kb   = bid & 15;   // xcd = bid%8 -> 2 k-blocks per XCD: W L2-resident
  const int mg   = bid >> 4;   // 0..15, 1024 rows each
  const int tid  = threadIdx.x;
  const int lane = tid & 63;
  const int w    = tid >> 6;   // wave 0..7 -> out-col slice of 32
  const int ln   = lane & 15;
  const int lk   = lane >> 4;  // 0..3

  const float* xbase = x   + (size_t)(mg * 1024) * INF + kb * 256;
  float*       obase = out + (size_t)(mg * 1024) * INF + kb * 256 + w * 32;

#define WAITVM(N) asm volatile("s_waitcnt vmcnt(" #N ")" ::: "memory")
#define LGKM0_BAR()                                                           \
  do {                                                                        \
    asm volatile("s_waitcnt lgkmcnt(0)" ::: "memory");                        \
    __builtin_amdgcn_s_barrier();                                             \
    asm volatile("" ::: "memory");                                            \
  } while (0)

  // 4 gload_lds/wave: one instruction = one contiguous 1 KB fp32 row -> LDS
#define PREFETCH(t)                                                           \
  _Pragma("unroll") for (int i_ = 0; i_ < 4; ++i_) {                          \
    const int r_ = w * 4 + i_;                                                \
    const float* gp_ = xbase + (size_t)((t) * TROWS + r_) * INF + lane * 4;   \
    __builtin_amdgcn_global_load_lds(                                         \
        (const __attribute__((address_space(1))) float*)gp_,                  \
        (__attribute__((address_space(3))) float*)(                           \
            xlds + ((t) % 3) * FTB + r_ * 1024),                              \
        16, 0, 0);                                                            \
  }

  // cvt stage: read fp32 tile from LDS ONCE, write bf16 tile (4 rows/wave)
#define CVT(t)                                                                \
  {                                                                           \
    const char* fb_ = xlds + ((t) % 3) * FTB;                                 \
    char*       ob_ = xlds + BF16OFF + ((t) & 1) * BTB;                       \
    _Pragma("unroll") for (int i_ = 0; i_ < 4; ++i_) {                        \
      const int r_ = w * 4 + i_;                                              \
      floatx4 v_ = *(const floatx4*)(fb_ + r_ * 1024 + lane * 16);            \
      unsigned p0_, p1_;                                                      \
      asm("v_cvt_pk_bf16_f32 %0, %1, %2" : "=v"(p0_) : "v"(v_[0]), "v"(v_[1])); \
      asm("v_cvt_pk_bf16_f32 %0, %1, %2" : "=v"(p1_) : "v"(v_[2]), "v"(v_[3])); \
      uint2v u_; u_[0] = p0_; u_[1] = p1_;                                    \
      *(uint2v*)(ob_ + r_ * RS + lane * 8) = u_;                              \
    }                                                                         \
  }

  // 16 ds_read_b128 + 32 MFMA per tile per wave (frag: x[mi*16+ln][kc*32+lk*8+e])
#define COMPUTE(t)                                                            \
  {                                                                           \
    const char* bb_ = xlds + BF16OFF + ((t) & 1) * BTB;                       \
    _Pragma("unroll") for (int a_ = 0; a_ < 4; ++a_)                          \
      _Pragma("unroll") for (int e_ = 0; e_ < 4; ++e_) acc[a_][e_] = 0.0f;    \
    _Pragma("unroll") for (int kc_ = 0; kc_ < 8; ++kc_) {                     \
      short8 xf_[2];                                                          \
      _Pragma("unroll") for (int mi_ = 0; mi_ < 2; ++mi_)                     \
        xf_[mi_] = *(const short8*)(bb_ + (mi_ * 16 + ln) * RS + kc_ * 64 + lk * 16); \
      _Pragma("unroll") for (int mi_ = 0; mi_ < 2; ++mi_)                     \
        _Pragma("unroll") for (int ni_ = 0; ni_ < 2; ++ni_)                   \
          acc[mi_ * 2 + ni_] = __builtin_amdgcn_mfma_f32_16x16x32_bf16(       \
              wf[ni_][kc_], xf_[mi_], acc[mi_ * 2 + ni_], 0, 0, 0);           \
    }                                                                         \
  }

  // frag D[n][m]: m(row) = mi*16 + ln, n(col) = ni*16 + lk*4 + j -> dwordx4
#define STOREACC(t)                                                           \
  _Pragma("unroll") for (int mi_ = 0; mi_ < 2; ++mi_)                         \
    _Pragma("unroll") for (int ni_ = 0; ni_ < 2; ++ni_) {                     \
      floatx4 r_ = acc[mi_ * 2 + ni_];                                        \
      _Pragma("unroll") for (int j_ = 0; j_ < 4; ++j_) r_[j_] += bv[ni_][j_]; \
      *(floatx4*)(obase + (size_t)((t) * TROWS + mi_ * 16 + ln) * INF +       \
                  ni_ * 16 + lk * 4) = r_;                                    \
    }

  // ---- prologue ----
  PREFETCH(0) PREFETCH(1) PREFETCH(2)

  short8 wf[2][8];  // wave w cols [w*32, w*32+32): A-layout [row=n (ln)][k=lk*8+e]
  {
    const float* wp = W + (size_t)kb * 65536 + (w * 32 + ln) * 256 + lk * 8;
#pragma unroll
    for (int ni = 0; ni < 2; ++ni)
#pragma unroll
      for (int kc = 0; kc < 8; ++kc) {
        const float* s = wp + ni * 16 * 256 + kc * 32;
        floatx4 v0 = *(const floatx4*)s;
        floatx4 v1 = *(const floatx4*)(s + 4);
        short8 u;
#pragma unroll
        for (int j = 0; j < 4; ++j) {
          u[j]     = (short)f2bf(v0[j]);
          u[4 + j] = (short)f2bf(v1[j]);
        }
        wf[ni][kc] = u;
      }
  }
  floatx4 bv[2];
#pragma unroll
  for (int ni = 0; ni < 2; ++ni)
    bv[ni] = *(const floatx4*)(bias + kb * 256 + w * 32 + ni * 16 + lk * 4);

  floatx4 acc[4];

  // certify fp32 tiles 0,1 (newer than PF(1) = PF(2) only = 4); cvt tile 0
  WAITVM(4);
  CVT(0)

  // ---- peeled iterations 0,1 (pipeline not yet full: smaller wait counts) ----
  // iter 0: tile 1 already certified by WAITVM(4) above
  LGKM0_BAR();                 // flush CVT(0); all waves ready
  PREFETCH(3)
  CVT(1)
  COMPUTE(0)
  STOREACC(0)
  // iter 1: certify tile 2: newer-than-PF(2) = PF(3)[4] + stores(0)[4] = 8
  WAITVM(8); LGKM0_BAR();
  PREFETCH(4)
  CVT(2)
  COMPUTE(1)
  STOREACC(1)

  // ---- steady loop t=2..28: WAITVM(12) ----
#pragma unroll 1
  for (int t = 2; t <= 28; ++t) {
    WAITVM(12); LGKM0_BAR();   // newer-than-PF(t+1): st(t-2)+PF(t+2)+st(t-1)=12
    PREFETCH(t + 3)
    CVT(t + 1)
    COMPUTE(t)
    STOREACC(t)
  }

  // ---- tail t=29,30,31 ----
  WAITVM(12); LGKM0_BAR();     // certify tile 30: st(27)+PF(31)+st(28) = 12
  CVT(30)
  COMPUTE(29)
  STOREACC(29)
  WAITVM(8); LGKM0_BAR();      // certify tile 31: st(28)+st(29) = 8
  CVT(31)
  COMPUTE(30)
  STOREACC(30)
  LGKM0_BAR();                 // flush CVT(31)
  COMPUTE(31)
  STOREACC(31)

#undef WAITVM
#undef LGKM0_BAR
#undef PREFETCH
#undef CVT
#undef COMPUTE
#undef STOREACC
}

extern "C" void kernel_launch(void* const* d_in, const int* in_sizes, int n_in,
                              void* d_out, int out_size, void* d_ws, size_t ws_size,
                              hipStream_t stream) {
  const float* x = (const float*)d_in[0];
  const float* W = (const float*)d_in[1];
  const float* b = (const float*)d_in[2];
  float* out = (float*)d_out;
  // 16 k-blocks x 16 m-groups = 256 WGs (1/CU), 512 threads (8 waves)
  hipLaunchKernelGGL(bd_gemm, dim3(256), dim3(512), 0, stream, x, W, b, out);
}